// Round 8
// baseline (1671.142 us; speedup 1.0000x reference)
//
#include <hip/hip_runtime.h>

#define H  64
#define G4 256   // 4*H

typedef float vf4 __attribute__((ext_vector_type(4)));

// fast sigmoid/tanh: v_exp_f32 + v_rcp_f32. Safe at +-inf:
//   x->-inf: exp(-x)=inf -> rcp(inf)=0 ; x->+inf: exp(-x)=0 -> rcp(1)=1
__device__ __forceinline__ float sigm(float x) {
    return __builtin_amdgcn_rcpf(1.0f + __expf(-x));
}
__device__ __forceinline__ float tanh_s(float x) {
    return fmaf(2.0f, sigm(2.0f * x), -1.0f);
}
__device__ __forceinline__ float bcast(float v, int lane) {
    return __int_as_float(__builtin_amdgcn_readlane(__float_as_int(v), lane));
}

// P2[v][e][g] = sum_h table[v][h] * w_ih[g*64+e][h] + b_ih + b_hh, table[0]=0.
// Layout [V][64][4] so the lstm consumer reads its 4 gate inputs as 1 dwordx4.
__global__ __launch_bounds__(256)
void proj_kernel(const float* __restrict__ emb,
                 const float* __restrict__ w_ih,
                 const float* __restrict__ b_ih,
                 const float* __restrict__ b_hh,
                 float* __restrict__ P,
                 int V)
{
    const int j  = threadIdx.x;       // gate row 0..255 (g = j>>6, e = j&63)
    const int v0 = blockIdx.x * 8;

    __shared__ float es[8][H];
    {
        int idx = j;
        #pragma unroll
        for (int rep = 0; rep < 2; ++rep, idx += 256) {
            int r = idx >> 6, col = idx & 63;
            int v = v0 + r;
            float val = 0.0f;
            if (v < V && v != 0) val = emb[v * H + col];   // padding_idx=0
            es[r][col] = val;
        }
    }

    vf4 w[16];
    const vf4* w4 = reinterpret_cast<const vf4*>(w_ih + j * H);
    #pragma unroll
    for (int i = 0; i < 16; ++i) w[i] = w4[i];

    float bias = b_ih[j] + b_hh[j];
    __syncthreads();

    const int slot = (j & 63) * 4 + (j >> 6);   // [e][g] position within row
    #pragma unroll
    for (int r = 0; r < 8; ++r) {
        int v = v0 + r;
        if (v >= V) break;
        float a0 = 0, a1 = 0, a2 = 0, a3 = 0;
        #pragma unroll
        for (int i = 0; i < 16; ++i) {
            a0 = fmaf(es[r][4*i+0], w[i][0], a0);
            a1 = fmaf(es[r][4*i+1], w[i][1], a1);
            a2 = fmaf(es[r][4*i+2], w[i][2], a2);
            a3 = fmaf(es[r][4*i+3], w[i][3], a3);
        }
        P[v * G4 + slot] = bias + ((a0 + a1) + (a2 + a3));
    }
}

// 8 waves (512 thr) per batch element: wave (g = wv>>1, kh = wv&1) computes
// gate g's row-l partial dot over k in [32kh, 32kh+32): 32 scalar fmaf +
// 32 readlane per lane per step. Exchange through pl[ph][gate][khalf][row]
// (stride-1, conflict-free), plain __syncthreads, double-buffered.
//
// BISECTION BUILD (R8): R6/R7 failed identically (absmax 0.254) with BOTH
// barrier styles -> deterministic bug in a construct they share. This build
// keeps the 8-wave structure but uses ONLY constructs proven in passing
// kernels: scalar-fmaf matvec with runtime-kb bcast (R3), __syncthreads
// (R0), LDS-staged epilogue (R3 verbatim). The v_pk_fma_f32 asm with an
// "s"-constrained vf2 built from runtime-index readlanes — the prime
// miscompile suspect — is REMOVED.
__global__ __launch_bounds__(512, 2)
void lstm_kernel(const int* __restrict__ x,        // [B,T]
                 const float* __restrict__ P2,     // [V][64][4]
                 const float* __restrict__ w_hh,   // [4H,H] (forward)
                 const float* __restrict__ w_ih_b, // [4H,H]
                 const float* __restrict__ b_ih_b, // [4H]
                 const float* __restrict__ b_hh_b, // [4H]
                 const float* __restrict__ emb,    // [V,H]
                 const float* __restrict__ w_fc,   // [12,2H]
                 const float* __restrict__ b_fc,   // [12]
                 float* __restrict__ out,          // [B,12]
                 int T)
{
    const int b    = blockIdx.x;
    const int tid  = threadIdx.x;
    const int lane = tid & 63;
    const int wv   = tid >> 6;      // 0..7
    const int g    = wv >> 1;       // gate 0..3
    const int kh   = wv & 1;        // k-half
    const int kb   = kh * 32;

    __shared__ float pl[2][4][2][64];   // [phase][gate][khalf][row], 4KB
    __shared__ float hf_s[H];
    __shared__ float hb_s[H];
    __shared__ float e_s[H];

    // 32 resident weights/lane: w_hh[g*64+lane][kb:kb+32]
    float w[32];
    {
        const vf4* wr = reinterpret_cast<const vf4*>(w_hh + (g * 64 + lane) * H + kb);
        #pragma unroll
        for (int i = 0; i < 8; ++i) {
            vf4 t = wr[i];
            w[4*i] = t.x; w[4*i+1] = t.y; w[4*i+2] = t.z; w[4*i+3] = t.w;
        }
    }

    const int* __restrict__ xrow = x + (long)b * T;
    const float* __restrict__ Pme = P2 + lane * 4;

    float h = 0.0f;   // lane l holds h[l] (replicated in every wave)
    float c = 0.0f;

    int tok_next = (T > 1) ? xrow[1] : 0;
    vf4 p_cur = *reinterpret_cast<const vf4*>(Pme + (size_t)xrow[0] * G4);

    for (int t = 0; t < T; ++t) {
        // prefetch next step's 4 gate inputs (one dwordx4, L2-resident)
        vf4 p_next = *reinterpret_cast<const vf4*>(Pme + (size_t)tok_next * G4);
        int tok_next2 = (t + 2 < T) ? xrow[t + 2] : 0;

        // partial dot over k in [kb, kb+32): scalar fmaf, 4 accumulators
        // (exact R3-proven pattern: runtime-kb bcast + v_fma with sgpr src)
        float a0 = 0, a1 = 0, a2 = 0, a3 = 0;
        #pragma unroll
        for (int m = 0; m < 32; m += 4) {
            float h0 = bcast(h, kb + m + 0);
            float h1 = bcast(h, kb + m + 1);
            float h2 = bcast(h, kb + m + 2);
            float h3 = bcast(h, kb + m + 3);
            a0 = fmaf(w[m+0], h0, a0);
            a1 = fmaf(w[m+1], h1, a1);
            a2 = fmaf(w[m+2], h2, a2);
            a3 = fmaf(w[m+3], h3, a3);
        }
        float part = (a0 + a1) + (a2 + a3);

        const int ph = t & 1;
        pl[ph][g][kh][lane] = part;
        __syncthreads();

        // every lane: gather its row's 8 partials (stride-1, conflict-free)
        float si = (pl[ph][0][0][lane] + pl[ph][0][1][lane]) + p_cur[0];
        float sf = (pl[ph][1][0][lane] + pl[ph][1][1][lane]) + p_cur[1];
        float sg = (pl[ph][2][0][lane] + pl[ph][2][1][lane]) + p_cur[2];
        float so = (pl[ph][3][0][lane] + pl[ph][3][1][lane]) + p_cur[3];

        float i_ = sigm(si);
        float f_ = sigm(sf);
        float g_ = tanh_s(sg);
        float o_ = sigm(so);
        c = fmaf(f_, c, i_ * g_);
        h = o_ * tanh_s(c);

        p_cur    = p_next;
        tok_next = tok_next2;
    }

    // ---- epilogue (R3-verbatim structure, all barriers block-wide) ----
    // backward LSTM = one step (hs_b[0]) from zero state:
    // gates = w_ih_b . emb[last_token] + biases (f-gate irrelevant, c0=0).
    int tokL = xrow[T - 1];
    if (wv == 0) hf_s[lane] = h;
    if (tid < H) e_s[tid] = (tokL != 0) ? emb[(size_t)tokL * H + tid] : 0.0f;
    __syncthreads();

    float* gb_s = reinterpret_cast<float*>(pl);   // reuse partial buffer
    if (tid < 256) {
        float accb = 0.0f;
        const vf4* wb4 = reinterpret_cast<const vf4*>(w_ih_b + tid * H);
        #pragma unroll
        for (int i = 0; i < 16; ++i) {
            vf4 wq = wb4[i];
            accb = fmaf(wq[0], e_s[4*i+0], accb);
            accb = fmaf(wq[1], e_s[4*i+1], accb);
            accb = fmaf(wq[2], e_s[4*i+2], accb);
            accb = fmaf(wq[3], e_s[4*i+3], accb);
        }
        float gb = accb + b_ih_b[tid] + b_hh_b[tid];
        gb_s[tid] = ((tid >> 6) == 2) ? tanh_s(gb) : sigm(gb);
    }
    __syncthreads();

    if (tid < H) {
        float i_ = gb_s[tid];
        float gg = gb_s[2*H + tid];
        float go = gb_s[3*H + tid];
        float cb = i_ * gg;               // f*c0 = 0
        hb_s[tid] = go * tanh_s(cb);
    }
    __syncthreads();

    // final FC: y[b, j] = b_fc[j] + [h_f | h_b] . w_fc[j]
    if (tid < 12) {
        float acc = b_fc[tid];
        const float* wfc = w_fc + tid * (2 * H);
        #pragma unroll
        for (int k = 0; k < H; ++k) acc = fmaf(hf_s[k], wfc[k], acc);
        #pragma unroll
        for (int k = 0; k < H; ++k) acc = fmaf(hb_s[k], wfc[H + k], acc);
        out[b * 12 + tid] = acc;
    }
}

extern "C" void kernel_launch(void* const* d_in, const int* in_sizes, int n_in,
                              void* d_out, int out_size, void* d_ws, size_t ws_size,
                              hipStream_t stream)
{
    const int*   x      = (const int*)  d_in[0];
    const float* emb    = (const float*)d_in[1];
    const float* w_ih_f = (const float*)d_in[2];
    const float* w_hh_f = (const float*)d_in[3];
    const float* b_ih_f = (const float*)d_in[4];
    const float* b_hh_f = (const float*)d_in[5];
    const float* w_ih_b = (const float*)d_in[6];
    // d_in[7] = w_hh_b (unused: backward runs exactly one step from zero state)
    const float* b_ih_b = (const float*)d_in[8];
    const float* b_hh_b = (const float*)d_in[9];
    const float* w_fc   = (const float*)d_in[10];
    const float* b_fc   = (const float*)d_in[11];
    float* out = (float*)d_out;

    const int B = out_size / 12;
    const int T = in_sizes[0] / B;
    const int V = in_sizes[1] / H;

    float* Pf = (float*)d_ws;                   // [V][64][4] (2 MB)

    int pblocks = (V + 7) / 8;
    proj_kernel<<<pblocks, 256, 0, stream>>>(emb, w_ih_f, b_ih_f, b_hh_f, Pf, V);
    lstm_kernel<<<B, 512, 0, stream>>>(x, Pf, w_hh_f, w_ih_b, b_ih_b, b_hh_b,
                                       emb, w_fc, b_fc, out, T);
}

// Round 9
// 1150.849 us; speedup vs baseline: 1.4521x; 1.4521x over previous
//
#include <hip/hip_runtime.h>

#define H  64
#define G4 256   // 4*H

typedef float vf4 __attribute__((ext_vector_type(4)));

// fast sigmoid/tanh: v_exp_f32 + v_rcp_f32. Safe at +-inf:
//   x->-inf: exp(-x)=inf -> rcp(inf)=0 ; x->+inf: exp(-x)=0 -> rcp(1)=1
__device__ __forceinline__ float sigm(float x) {
    return __builtin_amdgcn_rcpf(1.0f + __expf(-x));
}
__device__ __forceinline__ float tanh_s(float x) {
    return fmaf(2.0f, sigm(2.0f * x), -1.0f);
}
__device__ __forceinline__ float bcast(float v, int lane) {
    return __int_as_float(__builtin_amdgcn_readlane(__float_as_int(v), lane));
}

// P2[v][e][g] = sum_h table[v][h] * w_ih[g*64+e][h] + b_ih + b_hh, table[0]=0.
// Layout [V][64][4] so the lstm consumer reads its 4 gate inputs as 1 dwordx4.
__global__ __launch_bounds__(256)
void proj_kernel(const float* __restrict__ emb,
                 const float* __restrict__ w_ih,
                 const float* __restrict__ b_ih,
                 const float* __restrict__ b_hh,
                 float* __restrict__ P,
                 int V)
{
    const int j  = threadIdx.x;       // gate row 0..255 (g = j>>6, e = j&63)
    const int v0 = blockIdx.x * 8;

    __shared__ float es[8][H];
    {
        int idx = j;
        #pragma unroll
        for (int rep = 0; rep < 2; ++rep, idx += 256) {
            int r = idx >> 6, col = idx & 63;
            int v = v0 + r;
            float val = 0.0f;
            if (v < V && v != 0) val = emb[v * H + col];   // padding_idx=0
            es[r][col] = val;
        }
    }

    vf4 w[16];
    const vf4* w4 = reinterpret_cast<const vf4*>(w_ih + j * H);
    #pragma unroll
    for (int i = 0; i < 16; ++i) w[i] = w4[i];

    float bias = b_ih[j] + b_hh[j];
    __syncthreads();

    const int slot = (j & 63) * 4 + (j >> 6);   // [e][g] position within row
    #pragma unroll
    for (int r = 0; r < 8; ++r) {
        int v = v0 + r;
        if (v >= V) break;
        float a0 = 0, a1 = 0, a2 = 0, a3 = 0;
        #pragma unroll
        for (int i = 0; i < 16; ++i) {
            a0 = fmaf(es[r][4*i+0], w[i][0], a0);
            a1 = fmaf(es[r][4*i+1], w[i][1], a1);
            a2 = fmaf(es[r][4*i+2], w[i][2], a2);
            a3 = fmaf(es[r][4*i+3], w[i][3], a3);
        }
        P[v * G4 + slot] = bias + ((a0 + a1) + (a2 + a3));
    }
}

// COMPILE-TIME lane base: every readlane gets a LITERAL index -> single
// v_readlane_b32. (R8 post-mortem: runtime `kb+m` indices are divergent-
// typed, so LLVM legalizes each readlane with an exec-waterfall loop,
// ~3x issue bloat — R3/R8 slow, and feeding waterfalled values into an
// "s"-constrained asm was R6/R7's miscompile.)
template<int KB>
__device__ __forceinline__ float partial_dot32(const float* __restrict__ w, float h) {
    float a0 = 0, a1 = 0, a2 = 0, a3 = 0;
    #pragma unroll
    for (int m = 0; m < 32; m += 4) {
        float h0 = bcast(h, KB + m + 0);
        float h1 = bcast(h, KB + m + 1);
        float h2 = bcast(h, KB + m + 2);
        float h3 = bcast(h, KB + m + 3);
        a0 = fmaf(w[m+0], h0, a0);
        a1 = fmaf(w[m+1], h1, a1);
        a2 = fmaf(w[m+2], h2, a2);
        a3 = fmaf(w[m+3], h3, a3);
    }
    return (a0 + a1) + (a2 + a3);
}

// 8 waves (512 thr) per batch element: wave (g = wv>>1, kh = wv&1) computes
// gate g's row-l partial dot over k in [32kh, 32kh+32): 32 scalar fmaf +
// 32 constant-index readlane. Exchange through pl[ph][gate][khalf][row]
// (stride-1, conflict-free), plain __syncthreads, double-buffered; every
// lane redundantly computes all 4 acts + c/h (h replicated per wave).
// Structure verified correct in R8 (absmax 1e-6).
__global__ __launch_bounds__(512, 2)
void lstm_kernel(const int* __restrict__ x,        // [B,T]
                 const float* __restrict__ P2,     // [V][64][4]
                 const float* __restrict__ w_hh,   // [4H,H] (forward)
                 const float* __restrict__ w_ih_b, // [4H,H]
                 const float* __restrict__ b_ih_b, // [4H]
                 const float* __restrict__ b_hh_b, // [4H]
                 const float* __restrict__ emb,    // [V,H]
                 const float* __restrict__ w_fc,   // [12,2H]
                 const float* __restrict__ b_fc,   // [12]
                 float* __restrict__ out,          // [B,12]
                 int T)
{
    const int b    = blockIdx.x;
    const int tid  = threadIdx.x;
    const int lane = tid & 63;
    const int wv   = tid >> 6;      // 0..7
    const int g    = wv >> 1;       // gate 0..3
    const int kh   = wv & 1;        // k-half
    const int kb   = kh * 32;

    __shared__ float pl[2][4][2][64];   // [phase][gate][khalf][row], 4KB
    __shared__ float hf_s[H];
    __shared__ float hb_s[H];
    __shared__ float e_s[H];

    // 32 resident weights/lane: w_hh[g*64+lane][kb:kb+32]
    float w[32];
    {
        const vf4* wr = reinterpret_cast<const vf4*>(w_hh + (g * 64 + lane) * H + kb);
        #pragma unroll
        for (int i = 0; i < 8; ++i) {
            vf4 t = wr[i];
            w[4*i] = t.x; w[4*i+1] = t.y; w[4*i+2] = t.z; w[4*i+3] = t.w;
        }
    }

    const int* __restrict__ xrow = x + (long)b * T;
    const float* __restrict__ Pme = P2 + lane * 4;

    float h = 0.0f;   // lane l holds h[l] (replicated in every wave)
    float c = 0.0f;

    int tok_next = (T > 1) ? xrow[1] : 0;
    vf4 p_cur = *reinterpret_cast<const vf4*>(Pme + (size_t)xrow[0] * G4);

    for (int t = 0; t < T; ++t) {
        // prefetch next step's 4 gate inputs (one dwordx4, L2-resident)
        vf4 p_next = *reinterpret_cast<const vf4*>(Pme + (size_t)tok_next * G4);
        int tok_next2 = (t + 2 < T) ? xrow[t + 2] : 0;

        // partial dot over k in [kb, kb+32), compile-time lane base
        float part = (kh == 0) ? partial_dot32<0>(w, h)
                               : partial_dot32<32>(w, h);

        const int ph = t & 1;
        pl[ph][g][kh][lane] = part;
        __syncthreads();

        // every lane: gather its row's 8 partials (stride-1, conflict-free)
        float si = (pl[ph][0][0][lane] + pl[ph][0][1][lane]) + p_cur[0];
        float sf = (pl[ph][1][0][lane] + pl[ph][1][1][lane]) + p_cur[1];
        float sg = (pl[ph][2][0][lane] + pl[ph][2][1][lane]) + p_cur[2];
        float so = (pl[ph][3][0][lane] + pl[ph][3][1][lane]) + p_cur[3];

        float i_ = sigm(si);
        float f_ = sigm(sf);
        float g_ = tanh_s(sg);
        float o_ = sigm(so);
        c = fmaf(f_, c, i_ * g_);
        h = o_ * tanh_s(c);

        p_cur    = p_next;
        tok_next = tok_next2;
    }

    // ---- epilogue (R3/R8-verbatim structure, all barriers block-wide) ----
    // backward LSTM = one step (hs_b[0]) from zero state:
    // gates = w_ih_b . emb[last_token] + biases (f-gate irrelevant, c0=0).
    int tokL = xrow[T - 1];
    if (wv == 0) hf_s[lane] = h;
    if (tid < H) e_s[tid] = (tokL != 0) ? emb[(size_t)tokL * H + tid] : 0.0f;
    __syncthreads();

    float* gb_s = reinterpret_cast<float*>(pl);   // reuse partial buffer
    if (tid < 256) {
        float accb = 0.0f;
        const vf4* wb4 = reinterpret_cast<const vf4*>(w_ih_b + tid * H);
        #pragma unroll
        for (int i = 0; i < 16; ++i) {
            vf4 wq = wb4[i];
            accb = fmaf(wq[0], e_s[4*i+0], accb);
            accb = fmaf(wq[1], e_s[4*i+1], accb);
            accb = fmaf(wq[2], e_s[4*i+2], accb);
            accb = fmaf(wq[3], e_s[4*i+3], accb);
        }
        float gb = accb + b_ih_b[tid] + b_hh_b[tid];
        gb_s[tid] = ((tid >> 6) == 2) ? tanh_s(gb) : sigm(gb);
    }
    __syncthreads();

    if (tid < H) {
        float i_ = gb_s[tid];
        float gg = gb_s[2*H + tid];
        float go = gb_s[3*H + tid];
        float cb = i_ * gg;               // f*c0 = 0
        hb_s[tid] = go * tanh_s(cb);
    }
    __syncthreads();

    // final FC: y[b, j] = b_fc[j] + [h_f | h_b] . w_fc[j]
    if (tid < 12) {
        float acc = b_fc[tid];
        const float* wfc = w_fc + tid * (2 * H);
        #pragma unroll
        for (int k = 0; k < H; ++k) acc = fmaf(hf_s[k], wfc[k], acc);
        #pragma unroll
        for (int k = 0; k < H; ++k) acc = fmaf(hb_s[k], wfc[H + k], acc);
        out[b * 12 + tid] = acc;
    }
}

extern "C" void kernel_launch(void* const* d_in, const int* in_sizes, int n_in,
                              void* d_out, int out_size, void* d_ws, size_t ws_size,
                              hipStream_t stream)
{
    const int*   x      = (const int*)  d_in[0];
    const float* emb    = (const float*)d_in[1];
    const float* w_ih_f = (const float*)d_in[2];
    const float* w_hh_f = (const float*)d_in[3];
    const float* b_ih_f = (const float*)d_in[4];
    const float* b_hh_f = (const float*)d_in[5];
    const float* w_ih_b = (const float*)d_in[6];
    // d_in[7] = w_hh_b (unused: backward runs exactly one step from zero state)
    const float* b_ih_b = (const float*)d_in[8];
    const float* b_hh_b = (const float*)d_in[9];
    const float* w_fc   = (const float*)d_in[10];
    const float* b_fc   = (const float*)d_in[11];
    float* out = (float*)d_out;

    const int B = out_size / 12;
    const int T = in_sizes[0] / B;
    const int V = in_sizes[1] / H;

    float* Pf = (float*)d_ws;                   // [V][64][4] (2 MB)

    int pblocks = (V + 7) / 8;
    proj_kernel<<<pblocks, 256, 0, stream>>>(emb, w_ih_f, b_ih_f, b_hh_f, Pf, V);
    lstm_kernel<<<B, 512, 0, stream>>>(x, Pf, w_hh_f, w_ih_b, b_ih_b, b_hh_b,
                                       emb, w_fc, b_fc, out, T);
}